// Round 12
// baseline (29.724 us; speedup 1.0000x reference)
//
#include <hip/hip_runtime.h>

#define VDIM 20
#define NPAIR 190
#define NT 12            // 12 pair-tiles of 16 (190 -> 192)
#define EMB 64
#define ERS2 72          // f16 row stride (144 B = 9 x 16B blocks, odd -> 2-way max banking)

typedef __attribute__((ext_vector_type(8))) _Float16 f16x8;  // MFMA A/B frag (4 VGPR)
typedef __attribute__((ext_vector_type(4))) _Float16 f16x4;
typedef __attribute__((ext_vector_type(2))) _Float16 f16x2;
typedef __attribute__((ext_vector_type(4))) float    f32x4;

__device__ __forceinline__ f16x8 pack8(f32x4 a, f32x4 b) {
    auto p0 = __builtin_amdgcn_cvt_pkrtz(a[0], a[1]);  // v_cvt_pkrtz_f16_f32
    auto p1 = __builtin_amdgcn_cvt_pkrtz(a[2], a[3]);
    auto p2 = __builtin_amdgcn_cvt_pkrtz(b[0], b[1]);
    auto p3 = __builtin_amdgcn_cvt_pkrtz(b[2], b[3]);
    f16x8 r;
    r[0] = p0[0]; r[1] = p0[1]; r[2] = p1[0]; r[3] = p1[1];
    r[4] = p2[0]; r[5] = p2[1]; r[6] = p3[0]; r[7] = p3[1];
    return r;
}

__device__ __forceinline__ int pk16(float a, float b) {      // 2xf16 in one u32
    auto p = __builtin_amdgcn_cvt_pkrtz(a, b);
    int r; __builtin_memcpy(&r, &p, 4); return r;
}
__device__ __forceinline__ int pkadd16(int x, int y) {       // v_pk_add_f16
    f16x2 a, b;
    __builtin_memcpy(&a, &x, 4); __builtin_memcpy(&b, &y, 4);
    a = a + b;
    int r; __builtin_memcpy(&r, &a, 4); return r;
}

__global__ __launch_bounds__(256, 3)
void afm_fwd(const int* __restrict__ feats, const float* __restrict__ fvals,
             const float* __restrict__ emb, const float* __restrict__ btab,
             const float* __restrict__ gbias, const float* __restrict__ w1,
             const float* __restrict__ b1, const float* __restrict__ w2,
             const float* __restrict__ pw, float* __restrict__ out, int B)
{
    __shared__ __align__(16) _Float16 ls_e[8][VDIM * ERS2];  // 2 slabs per wave

    const int tid  = threadIdx.x;
    const int wv   = tid >> 6;
    const int lane = tid & 63;
    const int g    = lane >> 4;
    const int a0   = lane & 15;
    const int b0   = blockIdx.x * 8 + wv * 2;   // wave owns samples b0, b0+1
    const int b1s  = b0 + 1;
    if (b0 >= B) return;                        // wave-uniform; no barriers below
    const bool a0v = a0 < 14;                   // validity of tile 11's lanes

    // ---- features/values: lanes 0-19 sample0, lanes 32-51 sample1 ----
    int ff = 0; float vv = 0.f;
    {
        int r = lane & 31, s = lane >> 5, sb = b0 + s;
        if (r < VDIM && sb < B) { ff = feats[sb * VDIM + r]; vv = fvals[sb * VDIM + r]; }
    }

    // ---- pair decode for all 12 tiles -> packed byte offsets (static array) ----
    int po[NT];
    #pragma unroll
    for (int nt = 0; nt < NT; ++nt) {
        int p = nt * 16 + a0;
        if (p >= NPAIR) p = 0;
        int i = (int)((39.0f - sqrtf((float)(1521 - 8 * p))) * 0.5f);
        int t  = (i * (39 - i)) >> 1;
        int t1 = ((i + 1) * (38 - i)) >> 1;
        if (p < t)        { --i; t = (i * (39 - i)) >> 1; }
        else if (p >= t1) { ++i; t = t1; }
        int j = p - t + i + 1;
        po[nt] = (i * (ERS2 * 2)) | ((j * (ERS2 * 2)) << 16);
    }

    // ---- A-frags in f16 from L2-hot tables (shared by both samples) ----
    f16x8 aw[2][2];                              // W1: row m=a0+16*mta, k=ks*32+g*8+e
    #pragma unroll
    for (int mta = 0; mta < 2; ++mta)
        #pragma unroll
        for (int ks = 0; ks < 2; ++ks) {
            const f32x4* wp = reinterpret_cast<const f32x4*>(
                                  w1 + (a0 + 16*mta) * EMB + ks*32 + g*8);
            aw[mta][ks] = pack8(wp[0], wp[1]);
        }
    f16x8 apw[2];                                // pred_w on row 0 -> s_p in C row 0
    {
        const f16x8 zz = {};
        #pragma unroll
        for (int ks = 0; ks < 2; ++ks) {
            const f32x4* pp = reinterpret_cast<const f32x4*>(pw + ks*32 + g*8);
            apw[ks] = (a0 == 0) ? pack8(pp[0], pp[1]) : zz;
        }
    }

    // ---- b1/w2 slices: att = mta*16 + g*4 + r ----
    f32x4 b1v[2], w2v[2];
    #pragma unroll
    for (int mta = 0; mta < 2; ++mta) {
        b1v[mta] = *reinterpret_cast<const f32x4*>(b1 + mta*16 + g*4);
        w2v[mta] = *reinterpret_cast<const f32x4*>(w2 + mta*16 + g*4);
    }

    // ---- first-order bias: per-half reduce ----
    float fbv = ((lane & 31) < VDIM) ? btab[ff] * vv : 0.f;
    #pragma unroll
    for (int off = 16; off; off >>= 1) fbv += __shfl_xor(fbv, off);
    const float gbv = gbias[0];

    // ---- gather both samples: 5 passes x 4 rows x 2 slabs ----
    _Float16* ew0 = ls_e[wv * 2];
    _Float16* ew1 = ls_e[wv * 2 + 1];
    #pragma unroll
    for (int q = 0; q < 5; ++q) {
        int   row = q * 4 + g;
        int   fI0 = __shfl(ff, row);        float vI0 = __shfl(vv, row);
        int   fI1 = __shfl(ff, 32 + row);   float vI1 = __shfl(vv, 32 + row);
        f32x4 ev0 = reinterpret_cast<const f32x4*>(emb + (size_t)fI0 * EMB)[a0];
        f32x4 ev1 = reinterpret_cast<const f32x4*>(emb + (size_t)fI1 * EMB)[a0];
        auto h00 = __builtin_amdgcn_cvt_pkrtz(ev0[0] * vI0, ev0[1] * vI0);
        auto h01 = __builtin_amdgcn_cvt_pkrtz(ev0[2] * vI0, ev0[3] * vI0);
        auto h10 = __builtin_amdgcn_cvt_pkrtz(ev1[0] * vI1, ev1[1] * vI1);
        auto h11 = __builtin_amdgcn_cvt_pkrtz(ev1[2] * vI1, ev1[3] * vI1);
        f16x4 hv0; hv0[0]=h00[0]; hv0[1]=h00[1]; hv0[2]=h01[0]; hv0[3]=h01[1];
        f16x4 hv1; hv1[0]=h10[0]; hv1[1]=h10[1]; hv1[2]=h11[0]; hv1[3]=h11[1];
        *reinterpret_cast<f16x4*>(reinterpret_cast<char*>(ew0) + row*(ERS2*2) + a0*8) = hv0;
        *reinterpret_cast<f16x4*>(reinterpret_cast<char*>(ew1) + row*(ERS2*2) + a0*8) = hv1;
    }
    asm volatile("s_waitcnt lgkmcnt(0)" ::: "memory");   // DS in-order within wave
    __builtin_amdgcn_wave_barrier();

    // ---- main: 12 pair-tiles x 2 samples, fully unrolled ----
    float num0 = 0.f, den0 = 0.f, num1 = 0.f, den1 = 0.f;
    const f32x4 z4 = (f32x4){0.f, 0.f, 0.f, 0.f};
    #pragma unroll
    for (int nt = 0; nt < NT; ++nt) {
        const int oi = po[nt] & 0xffff, oj = po[nt] >> 16;

        f32x4 acc00 = b1v[0], acc01 = b1v[1], accs0 = z4;
        f32x4 acc10 = b1v[0], acc11 = b1v[1], accs1 = z4;
        #pragma unroll
        for (int ks = 0; ks < 2; ++ks) {
            const char* c0 = reinterpret_cast<const char*>(ew0);
            const char* c1 = reinterpret_cast<const char*>(ew1);
            f16x8 ei0 = *reinterpret_cast<const f16x8*>(c0 + oi + ks*64 + g*16);
            f16x8 ej0 = *reinterpret_cast<const f16x8*>(c0 + oj + ks*64 + g*16);
            f16x8 ei1 = *reinterpret_cast<const f16x8*>(c1 + oi + ks*64 + g*16);
            f16x8 ej1 = *reinterpret_cast<const f16x8*>(c1 + oj + ks*64 + g*16);
            f16x8 pr0 = ei0 * ej0;                       // v_pk_mul_f16 x4
            f16x8 pr1 = ei1 * ej1;
            acc00 = __builtin_amdgcn_mfma_f32_16x16x32_f16(aw[0][ks], pr0, acc00, 0, 0, 0);
            acc01 = __builtin_amdgcn_mfma_f32_16x16x32_f16(aw[1][ks], pr0, acc01, 0, 0, 0);
            accs0 = __builtin_amdgcn_mfma_f32_16x16x32_f16(apw[ks],   pr0, accs0, 0, 0, 0);
            acc10 = __builtin_amdgcn_mfma_f32_16x16x32_f16(aw[0][ks], pr1, acc10, 0, 0, 0);
            acc11 = __builtin_amdgcn_mfma_f32_16x16x32_f16(aw[1][ks], pr1, acc11, 0, 0, 0);
            accs1 = __builtin_amdgcn_mfma_f32_16x16x32_f16(apw[ks],   pr1, accs1, 0, 0, 0);
        }
        // logit partials: relu-dot, vectorized (pk_max/pk_fma)
        f32x4 r0 = __builtin_elementwise_max(acc00, z4) * w2v[0]
                 + __builtin_elementwise_max(acc01, z4) * w2v[1];
        f32x4 r1 = __builtin_elementwise_max(acc10, z4) * w2v[0]
                 + __builtin_elementwise_max(acc11, z4) * w2v[1];
        float tl0 = (r0[0] + r0[1]) + (r0[2] + r0[3]);
        float tl1 = (r1[0] + r1[1]) + (r1[2] + r1[3]);
        // pack both samples' partials (x256: keep f16 well above denormals),
        // 2 shuffle hops shared by both samples
        int ti = pk16(tl0 * 256.f, tl1 * 256.f);
        ti = pkadd16(ti, __shfl_xor(ti, 16));
        ti = pkadd16(ti, __shfl_xor(ti, 32));
        f16x2 tf; __builtin_memcpy(&tf, &ti, 4);
        float w0 = 0.f, w1x = 0.f;
        if (nt < 11 || a0v) {                            // compile-time for nt<11
            w0  = __expf((float)tf[0] * (1.0f / 256.f));
            w1x = __expf((float)tf[1] * (1.0f / 256.f));
        }
        num0 = fmaf(w0,  accs0[0], num0);  den0 += w0;   // accs[0]: s_p on g==0 lanes
        num1 = fmaf(w1x, accs1[0], num1);  den1 += w1x;
    }

    // ---- reduce across a0 (num on g==0 lanes; den replicated over g) ----
    #pragma unroll
    for (int off = 8; off; off >>= 1) {
        num0 += __shfl_xor(num0, off);  den0 += __shfl_xor(den0, off);
        num1 += __shfl_xor(num1, off);  den1 += __shfl_xor(den1, off);
    }
    float fb1 = __shfl(fbv, 32);
    if (lane == 0) {
        out[b0] = num0 / den0 + fbv + gbv;
        if (b1s < B) out[b1s] = num1 / den1 + fb1 + gbv;
    }
}

extern "C" void kernel_launch(void* const* d_in, const int* in_sizes, int n_in,
                              void* d_out, int out_size, void* d_ws, size_t ws_size,
                              hipStream_t stream)
{
    const int*   feats = (const int*)  d_in[0];
    const float* fvals = (const float*)d_in[1];
    const float* emb   = (const float*)d_in[2];
    const float* btab  = (const float*)d_in[3];
    const float* gb    = (const float*)d_in[4];
    const float* w1    = (const float*)d_in[5];
    const float* b1    = (const float*)d_in[6];
    const float* w2    = (const float*)d_in[7];
    const float* pw    = (const float*)d_in[8];
    float*       out   = (float*)d_out;

    const int B = in_sizes[0] / VDIM;
    afm_fwd<<<(B + 7) / 8, 256, 0, stream>>>(feats, fvals, emb, btab, gb,
                                             w1, b1, w2, pw, out, B);
}

// Round 13
// 27.842 us; speedup vs baseline: 1.0676x; 1.0676x over previous
//
#include <hip/hip_runtime.h>

#define VDIM 20
#define NPAIR 190
#define NT 12            // 12 pair-tiles of 16 (190 -> 192)
#define EMB 64
#define ERS2 72          // f16 row stride (144 B = 9 x 16B blocks, odd -> 2-way max banking)

typedef __attribute__((ext_vector_type(8))) _Float16 f16x8;  // MFMA A/B frag (4 VGPR)
typedef __attribute__((ext_vector_type(4))) _Float16 f16x4;
typedef __attribute__((ext_vector_type(4))) float    f32x4;

__device__ __forceinline__ f16x8 pack8(f32x4 a, f32x4 b) {
    auto p0 = __builtin_amdgcn_cvt_pkrtz(a[0], a[1]);  // v_cvt_pkrtz_f16_f32
    auto p1 = __builtin_amdgcn_cvt_pkrtz(a[2], a[3]);
    auto p2 = __builtin_amdgcn_cvt_pkrtz(b[0], b[1]);
    auto p3 = __builtin_amdgcn_cvt_pkrtz(b[2], b[3]);
    f16x8 r;
    r[0] = p0[0]; r[1] = p0[1]; r[2] = p1[0]; r[3] = p1[1];
    r[4] = p2[0]; r[5] = p2[1]; r[6] = p3[0]; r[7] = p3[1];
    return r;
}

__global__ __launch_bounds__(64, 4)   // 1-wave blocks: independent scheduling, no block tail
void afm_fwd(const int* __restrict__ feats, const float* __restrict__ fvals,
             const float* __restrict__ emb, const float* __restrict__ btab,
             const float* __restrict__ gbias, const float* __restrict__ w1,
             const float* __restrict__ b1, const float* __restrict__ w2,
             const float* __restrict__ pw, float* __restrict__ out, int B)
{
    __shared__ __align__(16) _Float16 ls_e[2][VDIM * ERS2];  // 2 sample slabs (5.76 KB)

    const int lane = threadIdx.x & 63;
    const int g    = lane >> 4;
    const int a0   = lane & 15;
    const int b0   = blockIdx.x * 2;            // wave owns samples b0, b0+1
    const int b1s  = b0 + 1;
    if (b0 >= B) return;                        // wave-uniform; no barriers below

    // ---- features/values: lanes 0-19 sample0, lanes 32-51 sample1 ----
    int ff = 0; float vv = 0.f;
    {
        int r = lane & 31, s = lane >> 5, sb = b0 + s;
        if (r < VDIM && sb < B) { ff = feats[sb * VDIM + r]; vv = fvals[sb * VDIM + r]; }
    }

    // ---- A-frags in f16 from L2-hot tables (shared by both samples) ----
    f16x8 aw[2][2];                              // W1: row m=a0+16*mta, k=ks*32+g*8+e
    #pragma unroll
    for (int mta = 0; mta < 2; ++mta)
        #pragma unroll
        for (int ks = 0; ks < 2; ++ks) {
            const f32x4* wp = reinterpret_cast<const f32x4*>(
                                  w1 + (a0 + 16*mta) * EMB + ks*32 + g*8);
            aw[mta][ks] = pack8(wp[0], wp[1]);
        }
    f16x8 apw[2];                                // pred_w on row 0 -> s_p in C row 0
    {
        const f16x8 zz = {};
        #pragma unroll
        for (int ks = 0; ks < 2; ++ks) {
            const f32x4* pp = reinterpret_cast<const f32x4*>(pw + ks*32 + g*8);
            apw[ks] = (a0 == 0) ? pack8(pp[0], pp[1]) : zz;
        }
    }

    // ---- b1/w2 slices: att = mta*16 + g*4 + r ----
    f32x4 b1v[2], w2v[2];
    #pragma unroll
    for (int mta = 0; mta < 2; ++mta) {
        b1v[mta] = *reinterpret_cast<const f32x4*>(b1 + mta*16 + g*4);
        w2v[mta] = *reinterpret_cast<const f32x4*>(w2 + mta*16 + g*4);
    }

    // ---- first-order bias: per-half reduce ----
    float fbv = ((lane & 31) < VDIM) ? btab[ff] * vv : 0.f;
    #pragma unroll
    for (int off = 16; off; off >>= 1) fbv += __shfl_xor(fbv, off);
    const float gbv = gbias[0];

    // ---- gather both samples: 5 passes x 4 rows x 2 slabs ----
    _Float16* ew0 = ls_e[0];
    _Float16* ew1 = ls_e[1];
    #pragma unroll
    for (int q = 0; q < 5; ++q) {
        int   row = q * 4 + g;
        int   fI0 = __shfl(ff, row);        float vI0 = __shfl(vv, row);
        int   fI1 = __shfl(ff, 32 + row);   float vI1 = __shfl(vv, 32 + row);
        f32x4 ev0 = reinterpret_cast<const f32x4*>(emb + (size_t)fI0 * EMB)[a0];
        f32x4 ev1 = reinterpret_cast<const f32x4*>(emb + (size_t)fI1 * EMB)[a0];
        auto h00 = __builtin_amdgcn_cvt_pkrtz(ev0[0] * vI0, ev0[1] * vI0);
        auto h01 = __builtin_amdgcn_cvt_pkrtz(ev0[2] * vI0, ev0[3] * vI0);
        auto h10 = __builtin_amdgcn_cvt_pkrtz(ev1[0] * vI1, ev1[1] * vI1);
        auto h11 = __builtin_amdgcn_cvt_pkrtz(ev1[2] * vI1, ev1[3] * vI1);
        f16x4 hv0; hv0[0]=h00[0]; hv0[1]=h00[1]; hv0[2]=h01[0]; hv0[3]=h01[1];
        f16x4 hv1; hv1[0]=h10[0]; hv1[1]=h10[1]; hv1[2]=h11[0]; hv1[3]=h11[1];
        *reinterpret_cast<f16x4*>(reinterpret_cast<char*>(ew0) + row*(ERS2*2) + a0*8) = hv0;
        *reinterpret_cast<f16x4*>(reinterpret_cast<char*>(ew1) + row*(ERS2*2) + a0*8) = hv1;
    }
    asm volatile("s_waitcnt lgkmcnt(0)" ::: "memory");   // DS in-order within wave
    __builtin_amdgcn_wave_barrier();

    // ---- main: 12 pair-tiles x 2 samples; softmax without max-subtract ----
    float num0 = 0.f, den0 = 0.f, num1 = 0.f, den1 = 0.f;
    #pragma unroll 2
    for (int nt = 0; nt < NT; ++nt) {
        int p = nt * 16 + a0;
        bool valid = p < NPAIR;
        if (!valid) p = 0;
        // closed-form pair decode (shared by both samples)
        int i = (int)((39.0f - sqrtf((float)(1521 - 8 * p))) * 0.5f);
        int t  = (i * (39 - i)) >> 1;
        int t1 = ((i + 1) * (38 - i)) >> 1;
        if (p < t)        { --i; t = (i * (39 - i)) >> 1; }
        else if (p >= t1) { ++i; t = t1; }
        int j = p - t + i + 1;
        const int oi = i * (ERS2 * 2), oj = j * (ERS2 * 2);

        f32x4 acc00 = b1v[0], acc01 = b1v[1], accs0 = (f32x4){0.f,0.f,0.f,0.f};
        f32x4 acc10 = b1v[0], acc11 = b1v[1], accs1 = (f32x4){0.f,0.f,0.f,0.f};
        #pragma unroll
        for (int ks = 0; ks < 2; ++ks) {
            const char* c0 = reinterpret_cast<const char*>(ew0);
            const char* c1 = reinterpret_cast<const char*>(ew1);
            f16x8 ei0 = *reinterpret_cast<const f16x8*>(c0 + oi + ks*64 + g*16);
            f16x8 ej0 = *reinterpret_cast<const f16x8*>(c0 + oj + ks*64 + g*16);
            f16x8 ei1 = *reinterpret_cast<const f16x8*>(c1 + oi + ks*64 + g*16);
            f16x8 ej1 = *reinterpret_cast<const f16x8*>(c1 + oj + ks*64 + g*16);
            f16x8 pr0 = ei0 * ej0;                       // v_pk_mul_f16 x4
            f16x8 pr1 = ei1 * ej1;
            acc00 = __builtin_amdgcn_mfma_f32_16x16x32_f16(aw[0][ks], pr0, acc00, 0, 0, 0);
            acc01 = __builtin_amdgcn_mfma_f32_16x16x32_f16(aw[1][ks], pr0, acc01, 0, 0, 0);
            accs0 = __builtin_amdgcn_mfma_f32_16x16x32_f16(apw[ks],   pr0, accs0, 0, 0, 0);
            acc10 = __builtin_amdgcn_mfma_f32_16x16x32_f16(aw[0][ks], pr1, acc10, 0, 0, 0);
            acc11 = __builtin_amdgcn_mfma_f32_16x16x32_f16(aw[1][ks], pr1, acc11, 0, 0, 0);
            accs1 = __builtin_amdgcn_mfma_f32_16x16x32_f16(apw[ks],   pr1, accs1, 0, 0, 0);
        }
        float tl0 = 0.f, tl1 = 0.f;
        #pragma unroll
        for (int r = 0; r < 4; ++r) {
            tl0 += fmaxf(acc00[r], 0.f) * w2v[0][r];
            tl0 += fmaxf(acc01[r], 0.f) * w2v[1][r];
            tl1 += fmaxf(acc10[r], 0.f) * w2v[0][r];
            tl1 += fmaxf(acc11[r], 0.f) * w2v[1][r];
        }
        tl0 += __shfl_xor(tl0, 16);  tl1 += __shfl_xor(tl1, 16);
        tl0 += __shfl_xor(tl0, 32);  tl1 += __shfl_xor(tl1, 32);
        float w0 = valid ? __expf(tl0) : 0.f;
        float w1x = valid ? __expf(tl1) : 0.f;
        num0 = fmaf(w0,  accs0[0], num0);  den0 += w0;   // accs[0]: s_p on g==0 lanes
        num1 = fmaf(w1x, accs1[0], num1);  den1 += w1x;
    }

    // ---- reduce across a0 (num on g==0 lanes; den replicated over g) ----
    #pragma unroll
    for (int off = 8; off; off >>= 1) {
        num0 += __shfl_xor(num0, off);  den0 += __shfl_xor(den0, off);
        num1 += __shfl_xor(num1, off);  den1 += __shfl_xor(den1, off);
    }
    float fb1 = __shfl(fbv, 32);
    if (lane == 0) {
        out[b0] = num0 / den0 + fbv + gbv;
        if (b1s < B) out[b1s] = num1 / den1 + fb1 + gbv;
    }
}

extern "C" void kernel_launch(void* const* d_in, const int* in_sizes, int n_in,
                              void* d_out, int out_size, void* d_ws, size_t ws_size,
                              hipStream_t stream)
{
    const int*   feats = (const int*)  d_in[0];
    const float* fvals = (const float*)d_in[1];
    const float* emb   = (const float*)d_in[2];
    const float* btab  = (const float*)d_in[3];
    const float* gb    = (const float*)d_in[4];
    const float* w1    = (const float*)d_in[5];
    const float* b1    = (const float*)d_in[6];
    const float* w2    = (const float*)d_in[7];
    const float* pw    = (const float*)d_in[8];
    float*       out   = (float*)d_out;

    const int B = in_sizes[0] / VDIM;
    afm_fwd<<<(B + 1) / 2, 64, 0, stream>>>(feats, fvals, emb, btab, gb,
                                            w1, b1, w2, pw, out, B);
}